// Round 3
// baseline (59.229 us; speedup 1.0000x reference)
//
#include <hip/hip_runtime.h>
#include <hip/hip_bf16.h>

#define NBINS 32
#define LDS_STRIDE 264      // halfs; 528B row stride -> bank-quad (4*row + 4*slot) mod 32: uniform for b128 reads
#define NTHREADS 256
#define NVOX 884736         // 96^3 = 3456 * 256
#define BLOCKS_PER_BATCH 576
#define NCHUNKS 6           // 576 * 6 = 3456 slabs of 256 voxels
#define NSLOTS 8            // histogram copies to spread global atomics
#define TILE_HALVES (NBINS * LDS_STRIDE)

typedef __attribute__((ext_vector_type(8))) _Float16 half8;
typedef __attribute__((ext_vector_type(16))) float f32x16;
typedef __attribute__((ext_vector_type(4))) int i32x4;

// Parzen: preterm = 1/(2*sigma^2), sigma = 0.5/31 -> exponent in bin units: -2*(tt-b)^2
// 7 taps: dropped |d|>=3.5 taps have w <= e^-24.5 ~ 2e-11 (fp16-flushed to 0 anyway).
__device__ __forceinline__ void scatter_weights(_Float16* __restrict__ L, int tid, float x) {
    float tt = x * 31.0f;
    float kf = rintf(tt);
    int ki = (int)kf;
    float u = tt - kf;               // [-0.5, 0.5]
    float w[7];
    float s = 0.0f;
#pragma unroll
    for (int o = 0; o < 7; ++o) {
        float d = u - (float)(o - 3);
        float e = __expf(-2.0f * d * d);
        int b = ki + o - 3;
        bool valid = (b >= 0) && (b < NBINS);
        e = valid ? e : 0.0f;
        w[o] = e;
        s += e;
    }
    float rinv = 1.0f / s;
#pragma unroll
    for (int o = 0; o < 7; ++o) {
        int b = ki + o - 3;
        if (b >= 0 && b < NBINS)
            L[b * LDS_STRIDE + tid] = (_Float16)(w[o] * rinv);
    }
}

__device__ __forceinline__ void zero_tiles(_Float16* __restrict__ smem, int tid) {
    // each thread zeroes 64B (4 x b128) of the 256 data halfs in one row, per tile.
    // row = tid>>3, half-offset = (tid&7)*32. Pad halfs 256..263 are never read.
    int off = (tid >> 3) * LDS_STRIDE + (tid & 7) * 32;
    i32x4 z = {0, 0, 0, 0};
#pragma unroll
    for (int q = 0; q < 4; ++q) {
        *(i32x4*)&smem[off + q * 8] = z;
        *(i32x4*)&smem[TILE_HALVES + off + q * 8] = z;
    }
}

__global__ __launch_bounds__(NTHREADS, 4)
void mi_hist_kernel(const float* __restrict__ pred, const float* __restrict__ targ,
                    float* __restrict__ hist /* [NSLOTS][2][32][32] */) {
    __shared__ __attribute__((aligned(16))) _Float16 smem[2 * TILE_HALVES];
    _Float16* LA = smem;
    _Float16* LB = smem + TILE_HALVES;

    const int tid = threadIdx.x;
    const int bx = blockIdx.x;
    const int batch = blockIdx.y;
    const float* p = pred + (size_t)batch * NVOX;
    const float* t = targ + (size_t)batch * NVOX;

    const int wid = tid >> 6;
    const int lane = tid & 63;
    // mfma_f32_32x32x16_f16 A/B frag: lane holds row(col)=lane&31, k = 8*(lane>>5)+j.
    // wave `wid` covers K-quarter [wid*64, wid*64+64).
    const int row = lane & 31;
    const int a_base = row * LDS_STRIDE + wid * 64 + 8 * (lane >> 5);

    f32x16 acc;
#pragma unroll
    for (int r = 0; r < 16; ++r) acc[r] = 0.0f;

    zero_tiles(smem, tid);
    float pv = p[(size_t)bx * 256 + tid];
    float tv = t[(size_t)bx * 256 + tid];
    __syncthreads();

    for (int c = 0; c < NCHUNKS; ++c) {
        scatter_weights(LA, tid, pv);
        scatter_weights(LB, tid, tv);
        __syncthreads();                 // scatter visible before MFMA reads

#pragma unroll
        for (int kb = 0; kb < 4; ++kb) {
            half8 af = *(const half8*)&LA[a_base + kb * 16];
            half8 bf = *(const half8*)&LB[a_base + kb * 16];
            acc = __builtin_amdgcn_mfma_f32_32x32x16_f16(af, bf, acc, 0, 0, 0);
        }

        if (c + 1 < NCHUNKS) {
            size_t v = ((size_t)(c + 1) * BLOCKS_PER_BATCH + bx) * 256 + tid;
            float pn = p[v];
            float tn = t[v];
            __syncthreads();             // MFMA reads done before zeroing
            zero_tiles(smem, tid);
            __syncthreads();             // zero done before next scatter
            pv = pn; tv = tn;
        }
    }

    // C/D layout (32x32): col = lane&31, row = (reg&3) + 8*(reg>>2) + 4*(lane>>5)
    const int col = lane & 31;
    const int rlo = 4 * (lane >> 5);
    float* H = hist + ((size_t)(bx & (NSLOTS - 1)) * 2 + batch) * (NBINS * NBINS);
#pragma unroll
    for (int r = 0; r < 16; ++r) {
        int rowc = (r & 3) + 8 * (r >> 2) + rlo;
        atomicAdd(&H[rowc * NBINS + col], acc[r]);
    }
}

__global__ void mi_reduce_kernel(const float* __restrict__ hist, float* __restrict__ out) {
    __shared__ float s_pab[2 * NBINS * NBINS];
    __shared__ double s_pa[2][NBINS];
    __shared__ double s_pb[2][NBINS];
    __shared__ double s_red[256];
    const int tid = threadIdx.x;
    const double invN = 1.0 / (double)NVOX;

    for (int idx = tid; idx < 2 * NBINS * NBINS; idx += 256) {
        float s = 0.0f;
        for (int sl = 0; sl < NSLOTS; ++sl) s += hist[sl * 2 * NBINS * NBINS + idx];
        s_pab[idx] = s;
    }
    __syncthreads();

    if (tid < 64) {
        int b = tid >> 5, i = tid & 31;
        double s = 0.0;
        for (int j = 0; j < NBINS; ++j) s += (double)s_pab[(b * NBINS + i) * NBINS + j];
        s_pa[b][i] = s * invN;
    } else if (tid < 128) {
        int t2 = tid - 64;
        int b = t2 >> 5, j = t2 & 31;
        double s = 0.0;
        for (int i = 0; i < NBINS; ++i) s += (double)s_pab[(b * NBINS + i) * NBINS + j];
        s_pb[b][j] = s * invN;
    }
    __syncthreads();

    double acc = 0.0;
    for (int idx = tid; idx < 2 * NBINS * NBINS; idx += 256) {
        int b = idx >> 10;
        int cell = idx & 1023;
        int i = cell >> 5, j = cell & 31;
        double pab = (double)s_pab[idx] * invN;
        double papb = s_pa[b][i] * s_pb[b][j];
        acc += pab * log((pab + 1e-7) / (papb + 1e-7) + 1e-7);
    }
    s_red[tid] = acc;
    __syncthreads();
    for (int s2 = 128; s2 > 0; s2 >>= 1) {
        if (tid < s2) s_red[tid] += s_red[tid + s2];
        __syncthreads();
    }
    if (tid == 0) out[0] = (float)(-0.5 * s_red[0]);
}

extern "C" void kernel_launch(void* const* d_in, const int* in_sizes, int n_in,
                              void* d_out, int out_size, void* d_ws, size_t ws_size,
                              hipStream_t stream) {
    const float* pred = (const float*)d_in[0];
    const float* targ = (const float*)d_in[1];
    float* hist = (float*)d_ws;
    float* out = (float*)d_out;

    hipMemsetAsync(hist, 0, NSLOTS * 2 * NBINS * NBINS * sizeof(float), stream);
    dim3 grid(BLOCKS_PER_BATCH, 2);
    hipLaunchKernelGGL(mi_hist_kernel, grid, dim3(NTHREADS), 0, stream, pred, targ, hist);
    hipLaunchKernelGGL(mi_reduce_kernel, dim3(1), dim3(256), 0, stream, hist, out);
}

// Round 4
// 33.732 us; speedup vs baseline: 1.7559x; 1.7559x over previous
//
#include <hip/hip_runtime.h>
#include <hip/hip_bf16.h>

#define NBINS 32
#define LDS_STRIDE 264      // halfs; 528B row stride
#define NTHREADS 256
#define NVOX 884736         // 96^3 = 3456 * 256
#define NSLABS 3456
#define BPB 512             // blocks per batch -> grid 1024 = exactly 4 blocks/CU
#define NSLOTS 16           // histogram copies to spread global atomics
#define TILE_HALVES (NBINS * LDS_STRIDE)

typedef __attribute__((ext_vector_type(8))) _Float16 half8;
typedef __attribute__((ext_vector_type(16))) float f32x16;
typedef __attribute__((ext_vector_type(4))) int i32x4;

// Parzen: preterm = 1/(2*sigma^2), sigma = 0.5/31 -> exponent in bin units: -2*(tt-b)^2
// 7 taps: dropped taps have w <= e^-24.5 ~ 2e-11 (fp16-flushed to 0 anyway).
// Each thread owns LDS column `tid`: it zeroes its OWN previous taps then writes
// the new ones (same-thread ds ops are ordered) -> no zero pass, no extra barrier.
__device__ __forceinline__ void scatter_rewrite(_Float16* __restrict__ L, int tid, float x,
                                                int& ki_old, bool zero_old) {
    float tt = x * 31.0f;
    float kf = rintf(tt);
    int ki = (int)kf;
    float u = tt - kf;               // [-0.5, 0.5]
    if (zero_old) {
#pragma unroll
        for (int o = 0; o < 7; ++o) {
            int b = ki_old + o - 3;
            if (b >= 0 && b < NBINS) L[b * LDS_STRIDE + tid] = (_Float16)0.0f;
        }
    }
    float w[7];
    float s = 0.0f;
#pragma unroll
    for (int o = 0; o < 7; ++o) {
        float d = u - (float)(o - 3);
        float e = __expf(-2.0f * d * d);
        int b = ki + o - 3;
        bool valid = (b >= 0) && (b < NBINS);
        e = valid ? e : 0.0f;
        w[o] = e;
        s += e;
    }
    float rinv = 1.0f / s;
#pragma unroll
    for (int o = 0; o < 7; ++o) {
        int b = ki + o - 3;
        if (b >= 0 && b < NBINS)
            L[b * LDS_STRIDE + tid] = (_Float16)(w[o] * rinv);
    }
    ki_old = ki;
}

__global__ __launch_bounds__(NTHREADS, 4)
void mi_hist_kernel(const float* __restrict__ pred, const float* __restrict__ targ,
                    float* __restrict__ hist /* [NSLOTS][2][32][32] */) {
    __shared__ __attribute__((aligned(16))) _Float16 smem[2 * TILE_HALVES];
    _Float16* LA = smem;
    _Float16* LB = smem + TILE_HALVES;

    const int tid = threadIdx.x;
    const int bx = blockIdx.x;
    const int batch = blockIdx.y;
    const float* p = pred + (size_t)batch * NVOX;
    const float* t = targ + (size_t)batch * NVOX;

    const int wid = tid >> 6;
    const int lane = tid & 63;
    // mfma_f32_32x32x16_f16 A/B frag: row(col)=lane&31, k = 8*(lane>>5)+j.
    // wave `wid` covers K-quarter [wid*64, wid*64+64) -> K-split partials.
    const int frag_off = (lane & 31) * LDS_STRIDE + wid * 64 + 8 * (lane >> 5);

    // 3456 slabs/batch = 512*6 + 384 -> blocks 0..383 run 7 chunks, rest 6 (block-uniform)
    const int nchunks = (bx < 384) ? 7 : 6;

    f32x16 acc;
#pragma unroll
    for (int r = 0; r < 16; ++r) acc[r] = 0.0f;

    // prologue: zero both tiles once (incl. pad), prefetch chunk 0
    {
        i32x4 z = {0, 0, 0, 0};
        i32x4* zp = (i32x4*)smem;
        for (int i = tid; i < (2 * TILE_HALVES) / 8; i += NTHREADS) zp[i] = z;
    }
    float pv = p[(size_t)bx * 256 + tid];
    float tv = t[(size_t)bx * 256 + tid];
    int kiA = 0, kiB = 0;
    __syncthreads();

    for (int c = 0; c < nchunks; ++c) {
        float pn = 0.0f, tn = 0.0f;
        if (c + 1 < nchunks) {               // prefetch next chunk (hides HBM latency)
            size_t v = ((size_t)(c + 1) * BPB + bx) * 256 + tid;
            pn = p[v];
            tn = t[v];
        }
        scatter_rewrite(LA, tid, pv, kiA, c > 0);
        scatter_rewrite(LB, tid, tv, kiB, c > 0);
        __syncthreads();                     // scatter visible before MFMA reads

#pragma unroll
        for (int kb = 0; kb < 4; ++kb) {
            half8 af = *(const half8*)&LA[frag_off + kb * 16];
            half8 bf = *(const half8*)&LB[frag_off + kb * 16];
            acc = __builtin_amdgcn_mfma_f32_32x32x16_f16(af, bf, acc, 0, 0, 0);
        }
        __syncthreads();                     // MFMA reads done before next rewrite
        pv = pn; tv = tn;
    }

    // block-level reduce: 4 waves hold K-split partials of the SAME 32x32.
    // C/D layout (32x32): col = lane&31, row = (reg&3) + 8*(reg>>2) + 4*(lane>>5)
    float* red = (float*)smem;               // 4 * 1024 floats = 16KB, reuses tile space
    const int col = lane & 31;
    const int rlo = 4 * (lane >> 5);
#pragma unroll
    for (int r = 0; r < 16; ++r) {
        int rowc = (r & 3) + 8 * (r >> 2) + rlo;
        red[wid * 1024 + rowc * 32 + col] = acc[r];
    }
    __syncthreads();
    float* H = hist + ((size_t)(bx & (NSLOTS - 1)) * 2 + batch) * 1024;
    for (int idx = tid; idx < 1024; idx += NTHREADS) {
        float s = red[idx] + red[1024 + idx] + red[2048 + idx] + red[3072 + idx];
        atomicAdd(&H[idx], s);
    }
}

__global__ void mi_reduce_kernel(const float* __restrict__ hist, float* __restrict__ out) {
    __shared__ float s_pab[2 * NBINS * NBINS];
    __shared__ double s_pa[2][NBINS];
    __shared__ double s_pb[2][NBINS];
    __shared__ double s_red[256];
    const int tid = threadIdx.x;
    const double invN = 1.0 / (double)NVOX;

    // sum the NSLOTS copies, vectorized float4 across cells
    for (int g = tid; g < 512; g += 256) {
        float4 s = make_float4(0.f, 0.f, 0.f, 0.f);
        for (int sl = 0; sl < NSLOTS; ++sl) {
            float4 v = ((const float4*)hist)[sl * 512 + g];
            s.x += v.x; s.y += v.y; s.z += v.z; s.w += v.w;
        }
        ((float4*)s_pab)[g] = s;
    }
    __syncthreads();

    if (tid < 64) {
        int b = tid >> 5, i = tid & 31;
        double s = 0.0;
        for (int j = 0; j < NBINS; ++j) s += (double)s_pab[(b * NBINS + i) * NBINS + j];
        s_pa[b][i] = s * invN;
    } else if (tid < 128) {
        int t2 = tid - 64;
        int b = t2 >> 5, j = t2 & 31;
        double s = 0.0;
        for (int i = 0; i < NBINS; ++i) s += (double)s_pab[(b * NBINS + i) * NBINS + j];
        s_pb[b][j] = s * invN;
    }
    __syncthreads();

    double acc = 0.0;
    for (int idx = tid; idx < 2 * NBINS * NBINS; idx += 256) {
        int b = idx >> 10;
        int cell = idx & 1023;
        int i = cell >> 5, j = cell & 31;
        double pab = (double)s_pab[idx] * invN;
        double papb = s_pa[b][i] * s_pb[b][j];
        acc += pab * log((pab + 1e-7) / (papb + 1e-7) + 1e-7);
    }
    s_red[tid] = acc;
    __syncthreads();
    for (int s2 = 128; s2 > 0; s2 >>= 1) {
        if (tid < s2) s_red[tid] += s_red[tid + s2];
        __syncthreads();
    }
    if (tid == 0) out[0] = (float)(-0.5 * s_red[0]);
}

extern "C" void kernel_launch(void* const* d_in, const int* in_sizes, int n_in,
                              void* d_out, int out_size, void* d_ws, size_t ws_size,
                              hipStream_t stream) {
    const float* pred = (const float*)d_in[0];
    const float* targ = (const float*)d_in[1];
    float* hist = (float*)d_ws;
    float* out = (float*)d_out;

    hipMemsetAsync(hist, 0, NSLOTS * 2 * NBINS * NBINS * sizeof(float), stream);
    dim3 grid(BPB, 2);
    hipLaunchKernelGGL(mi_hist_kernel, grid, dim3(NTHREADS), 0, stream, pred, targ, hist);
    hipLaunchKernelGGL(mi_reduce_kernel, dim3(1), dim3(256), 0, stream, hist, out);
}